// Round 6
// baseline (660.867 us; speedup 1.0000x reference)
//
#include <hip/hip_runtime.h>

#define NNODES 100000
#define NEDGES 1600000
#define ET (NEDGES + NNODES)      // 1,700,000 incl. self loops
#define NBUCK 196                 // ceil(100000/512) buckets of 512 nodes
#define NEG 0.2f
#define BNEPS 1e-5f
#define EPB 4096                  // edges per block, bucket passes
#define NBLK_E ((ET + EPB - 1) / EPB)   // 416

typedef __attribute__((ext_vector_type(8))) short short8;
typedef __attribute__((ext_vector_type(4))) float floatx4;
typedef __attribute__((ext_vector_type(2))) float floatx2;

__device__ __forceinline__ unsigned short f2b(float x) {
    unsigned int u = __float_as_uint(x);
    u += 0x7fff + ((u >> 16) & 1);        // RNE
    return (unsigned short)(u >> 16);
}
__device__ __forceinline__ float b2f(unsigned short u) {
    return __uint_as_float(((unsigned int)u) << 16);
}
__device__ __forceinline__ float blo2f(unsigned int v) {
    return __uint_as_float(v << 16);
}
__device__ __forceinline__ float bhi2f(unsigned int v) {
    return __uint_as_float(v & 0xffff0000u);
}
__device__ __forceinline__ floatx2 u2f2(unsigned int v) {
    floatx2 r;
    r.x = __uint_as_float(v << 16);
    r.y = __uint_as_float(v & 0xffff0000u);
    return r;
}

// ---------------- edge decode (int32 vs int64 hedge) ----------------
__device__ __forceinline__ int edge_src(const int* ei, int e, int w64) {
    if (e >= NEDGES) return e - NEDGES;          // self loop
    return w64 ? ei[2 * e] : ei[e];
}
__device__ __forceinline__ int edge_dst(const int* ei, int e, int w64) {
    if (e >= NEDGES) return e - NEDGES;
    return w64 ? ei[2 * (NEDGES + e)] : ei[NEDGES + e];
}

// ---------------- prep: dtype detect + W transpose + scratch zeroing ----------------
__global__ void k_prep(const float* __restrict__ W1, const float* __restrict__ W2,
                       unsigned short* __restrict__ WT1, unsigned short* __restrict__ WT2,
                       const int* ei, int* flag, int* bcnt, int* done, float* bnstat,
                       int* dhist) {
    int t = blockIdx.x * 256 + threadIdx.x;      // 16384 threads
    if (blockIdx.x == 0) {
        bcnt[threadIdx.x] = 0;
        if (threadIdx.x == 0) *done = 0;
        if (threadIdx.x == 1) {
            int is64 = 1;
            for (int j = 1; j < 16; j += 2)
                if (ei[j] != 0) is64 = 0;
            *flag = is64;
        }
    } else if (blockIdx.x == 1) {
        bnstat[threadIdx.x] = 0.f;
    } else if (blockIdx.x == 2) {
        bnstat[256 + threadIdx.x] = 0.f;
    } else if (blockIdx.x == 3) {
        dhist[threadIdx.x] = 0;
    }
    int k = t >> 7, n = t & 127;
    WT1[n * 128 + k] = f2b(W1[t]);
    WT2[n * 128 + k] = f2b(W2[t]);
}

// ---------------- CSR build pass A: bucket histogram (+inline scan, last block) ----
__global__ __launch_bounds__(256) void k_bhist(const int* __restrict__ ei,
                                               const int* flag, int* bcnt,
                                               int* done, int* bbase, int* bcur) {
    __shared__ int lc[256];
    __shared__ int lastf;
    int t = threadIdx.x;
    lc[t] = 0;
    __syncthreads();
    int w64 = *flag;
    int base = blockIdx.x * EPB;
    for (int j = 0; j < EPB / 512; j++) {
        int e = base + j * 512 + t * 2;          // 2 edges per thread
        if (e + 1 < NEDGES) {
            int d0, d1;
            if (w64) {
                int4 dv = *(const int4*)&ei[2 * (NEDGES + e)];
                d0 = dv.x; d1 = dv.z;
            } else {
                int2 dv = *(const int2*)&ei[NEDGES + e];
                d0 = dv.x; d1 = dv.y;
            }
            atomicAdd(&lc[d0 >> 9], 1);
            atomicAdd(&lc[d1 >> 9], 1);
        } else {
            for (int k = 0; k < 2; k++) {
                int ee = e + k;
                if (ee < ET) atomicAdd(&lc[edge_dst(ei, ee, w64) >> 9], 1);
            }
        }
    }
    __syncthreads();
    if (t < NBUCK && lc[t]) atomicAdd(&bcnt[t], lc[t]);
    __threadfence();
    __syncthreads();
    if (t == 0) lastf = (atomicAdd(done, 1) == gridDim.x - 1) ? 1 : 0;
    __syncthreads();
    if (!lastf) return;
    // inline 196-bucket exclusive scan
    int v = (t < NBUCK) ? atomicAdd(&bcnt[t], 0) : 0;
    __syncthreads();
    lc[t] = v;
    __syncthreads();
    for (int off = 1; off < 256; off <<= 1) {
        int add = (t >= off) ? lc[t - off] : 0;
        __syncthreads();
        lc[t] += add;
        __syncthreads();
    }
    int excl = lc[t] - v;
    if (t < NBUCK) { bbase[t] = excl; bcur[t] = excl; }
    if (t == NBUCK - 1) bbase[NBUCK] = excl + v;
}

// ---------------- pass C: partition packed pairs into bucket regions ----------------
// pairs packed: (src << 9) | (dst & 511); src < 2^17
__global__ __launch_bounds__(256) void k_bscatter(const int* __restrict__ ei,
                                                  const int* flag, int* bcur,
                                                  int* __restrict__ pairs) {
    __shared__ int lc[256];
    __shared__ int lbase[256];
    int t = threadIdx.x;
    lc[t] = 0;
    __syncthreads();
    int w64 = *flag;
    int base = blockIdx.x * EPB;
    for (int j = 0; j < EPB / 512; j++) {
        int e = base + j * 512 + t * 2;
        if (e + 1 < NEDGES) {
            int d0, d1;
            if (w64) {
                int4 dv = *(const int4*)&ei[2 * (NEDGES + e)];
                d0 = dv.x; d1 = dv.z;
            } else {
                int2 dv = *(const int2*)&ei[NEDGES + e];
                d0 = dv.x; d1 = dv.y;
            }
            atomicAdd(&lc[d0 >> 9], 1);
            atomicAdd(&lc[d1 >> 9], 1);
        } else {
            for (int k = 0; k < 2; k++) {
                int ee = e + k;
                if (ee < ET) atomicAdd(&lc[edge_dst(ei, ee, w64) >> 9], 1);
            }
        }
    }
    __syncthreads();
    if (t < NBUCK && lc[t]) lbase[t] = atomicAdd(&bcur[t], lc[t]);
    __syncthreads();
    for (int j = 0; j < EPB / 512; j++) {
        int e = base + j * 512 + t * 2;
        if (e + 1 < NEDGES) {
            int s0, s1, d0, d1;
            if (w64) {
                int4 sv = *(const int4*)&ei[2 * e];
                int4 dv = *(const int4*)&ei[2 * (NEDGES + e)];
                s0 = sv.x; s1 = sv.z; d0 = dv.x; d1 = dv.z;
            } else {
                int2 sv = *(const int2*)&ei[e];
                int2 dv = *(const int2*)&ei[NEDGES + e];
                s0 = sv.x; s1 = sv.y; d0 = dv.x; d1 = dv.y;
            }
            int p0 = atomicAdd(&lbase[d0 >> 9], 1);
            pairs[p0] = (s0 << 9) | (d0 & 511);
            int p1 = atomicAdd(&lbase[d1 >> 9], 1);
            pairs[p1] = (s1 << 9) | (d1 & 511);
        } else {
            for (int k = 0; k < 2; k++) {
                int ee = e + k;
                if (ee < ET) {
                    int src = edge_src(ei, ee, w64);
                    int dst = edge_dst(ei, ee, w64);
                    int pos = atomicAdd(&lbase[dst >> 9], 1);
                    pairs[pos] = (src << 9) | (dst & 511);
                }
            }
        }
    }
}

// ---------------- pass D: per-bucket counting sort -> rowptr + srcs (+deg hist) ------
__global__ __launch_bounds__(256) void k_bsort(const int* __restrict__ pairs,
                                               const int* __restrict__ bbase,
                                               int* __restrict__ rowptr,
                                               int* __restrict__ srcs,
                                               int* __restrict__ dhist) {
    __shared__ int ncnt[512];
    __shared__ int nbase[512];
    __shared__ int stmp[256];
    __shared__ int ldh[256];
    int b = blockIdx.x, t = threadIdx.x;
    ncnt[t] = 0; ncnt[t + 256] = 0; ldh[t] = 0;
    __syncthreads();
    int s0 = bbase[b], s1 = bbase[b + 1];
    int btot = s1 - s0;
    for (int i = s0 + t; i < s1; i += 256)
        atomicAdd(&ncnt[pairs[i] & 511], 1);
    __syncthreads();
    int c0 = ncnt[2 * t], c1 = ncnt[2 * t + 1];
    int s = c0 + c1;
    stmp[t] = s;
    __syncthreads();
    for (int off = 1; off < 256; off <<= 1) {
        int add = (t >= off) ? stmp[t - off] : 0;
        __syncthreads();
        stmp[t] += add;
        __syncthreads();
    }
    int excl = stmp[t] - s;
    nbase[2 * t] = excl;
    nbase[2 * t + 1] = excl + c0;
    __syncthreads();
    for (int l = t; l < 512; l += 256) {
        int node = b * 512 + l;
        if (node <= NNODES) rowptr[node] = s0 + nbase[l];
        if (node < NNODES) {
            int deg = ((l < 511) ? nbase[l + 1] : btot) - nbase[l];
            atomicAdd(&ldh[min(deg, 255)], 1);
        }
        ncnt[l] = nbase[l];            // becomes cursor
    }
    __syncthreads();
    for (int i = s0 + t; i < s1; i += 256) {
        int pr = pairs[i];
        int off = atomicAdd(&ncnt[pr & 511], 1);
        srcs[s0 + off] = ((unsigned int)pr) >> 9;
    }
    __syncthreads();
    if (ldh[t]) atomicAdd(&dhist[t], ldh[t]);
}

// ---------------- degree-sort: scan (descending) + permutation scatter ----------------
__global__ void k_dscan(const int* __restrict__ dhist, int* dcur) {
    __shared__ int sh[256];
    int t = threadIdx.x;
    int v = dhist[t];
    sh[t] = v;
    __syncthreads();
    for (int off = 1; off < 256; off <<= 1) {
        int add = (t >= off) ? sh[t - off] : 0;
        __syncthreads();
        sh[t] += add;
        __syncthreads();
    }
    int total = sh[255];
    dcur[t] = total - sh[t];          // bins ordered 255,254,...,0 (heavy first)
}

__global__ __launch_bounds__(256) void k_dperm(const int* __restrict__ rowptr,
                                               int* dcur, int* __restrict__ perm) {
    __shared__ int lc[256];
    __shared__ int lbase[256];
    int t = threadIdx.x;
    lc[t] = 0;
    __syncthreads();
    int n = blockIdx.x * 256 + t;
    int d = -1;
    if (n < NNODES) {
        d = min(rowptr[n + 1] - rowptr[n], 255);
        atomicAdd(&lc[d], 1);
    }
    __syncthreads();
    if (lc[t]) lbase[t] = atomicAdd(&dcur[t], lc[t]);
    __syncthreads();
    if (n < NNODES) {
        int pos = atomicAdd(&lbase[d], 1);
        perm[pos] = n;
    }
}

// ---------------- MFMA GEMM (+in-block BN/ELU on bf16 A) + fused scores ----------------
template<bool BN>
__global__ __launch_bounds__(256) void k_gemm(const void* __restrict__ Ain,
        const unsigned short* __restrict__ WTg,
        const float* __restrict__ sums, const float* __restrict__ sqs,
        const float* __restrict__ gamma, const float* __restrict__ beta,
        const float* __restrict__ a_s, const float* __restrict__ a_d,
        float* __restrict__ es, float* __restrict__ ed,
        unsigned short* __restrict__ hB, int n) {
    __shared__ unsigned short lA[64][136];
    __shared__ unsigned short lW[128][136];
    __shared__ float las[128], lad[128];
    __shared__ float lsc[128], lsh[128];
    int t = threadIdx.x;
    int row0 = blockIdx.x * 64;
    if (t < 128) { las[t] = a_s[t]; lad[t] = a_d[t]; }
    if (BN && t < 128) {
        float mu = sums[t] * (1.f / NNODES);
        float var = fmaxf(sqs[t] * (1.f / NNODES) - mu * mu, 0.f);
        float s = gamma[t] * rsqrtf(var + BNEPS);
        lsc[t] = s;
        lsh[t] = beta[t] - mu * s;
    }

    const uint4* wt4 = (const uint4*)WTg;
#pragma unroll
    for (int j = 0; j < 8; j++) {
        int idx = t + j * 256;
        *(uint4*)&lW[idx >> 4][(idx & 15) * 8] = wt4[idx];
    }
    if (BN) __syncthreads();   // lsc/lsh visible before A staging

    if (BN) {
        const uint4* Ab = (const uint4*)Ain;   // bf16 rows, 16 uint4 each
#pragma unroll
        for (int j = 0; j < 4; j++) {
            int idx = t + j * 256;
            int r = idx >> 4, seg = idx & 15;
            uint4 v = make_uint4(0, 0, 0, 0);
            if (row0 + r < n) v = Ab[(size_t)(row0 + r) * 16 + seg];
            float f[8];
            f[0] = blo2f(v.x); f[1] = bhi2f(v.x);
            f[2] = blo2f(v.y); f[3] = bhi2f(v.y);
            f[4] = blo2f(v.z); f[5] = bhi2f(v.z);
            f[6] = blo2f(v.w); f[7] = bhi2f(v.w);
            ushort4 u0, u1;
            unsigned short us[8];
#pragma unroll
            for (int k = 0; k < 8; k++) {
                int c = seg * 8 + k;
                float z = fmaf(f[k], lsc[c], lsh[c]);
                z = z > 0.f ? z : __expf(z) - 1.f;
                us[k] = f2b(z);
            }
            u0.x = us[0]; u0.y = us[1]; u0.z = us[2]; u0.w = us[3];
            u1.x = us[4]; u1.y = us[5]; u1.z = us[6]; u1.w = us[7];
            *(ushort4*)&lA[r][seg * 8] = u0;
            *(ushort4*)&lA[r][seg * 8 + 4] = u1;
        }
    } else {
        const float* Af = (const float*)Ain;
#pragma unroll
        for (int j = 0; j < 8; j++) {
            int idx = t + j * 256;
            int r = idx >> 5, c4 = idx & 31;
            float4 v = make_float4(0.f, 0.f, 0.f, 0.f);
            if (row0 + r < n) v = ((const float4*)Af)[(size_t)(row0 + r) * 32 + c4];
            ushort4 u;
            u.x = f2b(v.x); u.y = f2b(v.y); u.z = f2b(v.z); u.w = f2b(v.w);
            *(ushort4*)&lA[r][c4 * 4] = u;
        }
    }
    __syncthreads();

    int w = t >> 6, lane = t & 63;
    int m = lane & 15, q = lane >> 4;
    int arow = w * 16 + m;
    floatx4 acc[8];
#pragma unroll
    for (int ct = 0; ct < 8; ct++) acc[ct] = (floatx4)0.0f;

#pragma unroll
    for (int kt = 0; kt < 4; kt++) {
        int kb = kt * 32 + q * 8;
        short8 af = *(const short8*)&lA[arow][kb];
#pragma unroll
        for (int ct = 0; ct < 8; ct++) {
            short8 bf = *(const short8*)&lW[ct * 16 + m][kb];
            acc[ct] = __builtin_amdgcn_mfma_f32_16x16x32_bf16(af, bf, acc[ct], 0, 0, 0);
        }
    }

    __syncthreads();   // done reading lA as input; about to overwrite with C tile
#pragma unroll
    for (int ct = 0; ct < 8; ct++)
#pragma unroll
        for (int r = 0; r < 4; r++)
            lA[w * 16 + q * 4 + r][ct * 16 + m] = f2b(acc[ct][r]);
#pragma unroll
    for (int j = 0; j < 4; j++) {
        int idx = lane + j * 64;
        int r = idx >> 4, seg = idx & 15;
        int grow = row0 + w * 16 + r;
        if (grow < n) {
            uint4 v = *(const uint4*)&lA[w * 16 + r][seg * 8];
            ((uint4*)hB)[(size_t)grow * 16 + seg] = v;
        }
    }
    __syncthreads();
    // fused attention scores: 4 threads per row, 32 chans each
    int r = t >> 2, q4 = t & 3;
    float s1 = 0.f, s2 = 0.f;
#pragma unroll
    for (int k = 0; k < 32; k++) {
        int c = q4 * 32 + k;
        float v = b2f(lA[r][c]);
        s1 += v * las[c];
        s2 += v * lad[c];
    }
    s1 += __shfl_xor(s1, 1, 64); s1 += __shfl_xor(s1, 2, 64);
    s2 += __shfl_xor(s2, 1, 64); s2 += __shfl_xor(s2, 2, 64);
    if (q4 == 0 && row0 + r < n) { es[row0 + r] = s1; ed[row0 + r] = s2; }
}

// ---------------- fused softmax + weighted gather + BN stats ----------------
// quarter-wave per node, nodes degree-sorted via perm so the 4 nodes sharing
// a wave have near-equal degree (no divergence waste in the j-loop).
__global__ __launch_bounds__(256) void k_attn(const unsigned short* __restrict__ hB,
                                              const int* __restrict__ srcs,
                                              const int* __restrict__ rowptr,
                                              const int* __restrict__ perm,
                                              const float* __restrict__ es,
                                              const float* __restrict__ ed,
                                              const float* __restrict__ bias,
                                              unsigned short* __restrict__ haggB,
                                              float* __restrict__ gsum,
                                              float* __restrict__ gsq) {
    __shared__ float lds_s[4][128], lds_q[4][128];
    int widx = (blockIdx.x * 256 + threadIdx.x) >> 4;   // grid exact: widx < NNODES
    int w = perm[widx];
    int l = threadIdx.x & 15;
    int qb = threadIdx.x & 48;                       // quarter's base lane in wave
    int start = rowptr[w], end = rowptr[w + 1];
    float edv = ed[w];
    const uint4* hp4 = (const uint4*)hB;
    floatx2 a0 = {0.f, 0.f}, a1 = {0.f, 0.f}, a2 = {0.f, 0.f}, a3 = {0.f, 0.f};
    float den = 0.f;

    for (int chunk = start; chunk < end; chunk += 16) {
        int i = chunk + l;
        int sv = 0; float pv = 0.f;
        if (i < end) {
            sv = srcs[i];
            float e = es[sv] + edv;
            e = e > 0.f ? e : NEG * e;
            pv = __expf(e);
            den += pv;
        }
        int cnt = min(16, end - chunk);
        for (int j = 0; j < cnt; j++) {
            int   s0 = __shfl(sv, qb + j, 64);
            float p0 = __shfl(pv, qb + j, 64);
            uint4 h0 = hp4[(size_t)s0 * 16 + l];
            floatx2 P = {p0, p0};
            a0 += P * u2f2(h0.x); a1 += P * u2f2(h0.y);
            a2 += P * u2f2(h0.z); a3 += P * u2f2(h0.w);
        }
    }
    den += __shfl_xor(den, 1, 64); den += __shfl_xor(den, 2, 64);
    den += __shfl_xor(den, 4, 64); den += __shfl_xor(den, 8, 64);
    float inv = 1.f / den;                           // den > 0: self loop guaranteed
    const float2* b2p = (const float2*)bias;
    float2 c0 = b2p[l * 4 + 0], c1 = b2p[l * 4 + 1];
    float2 c2 = b2p[l * 4 + 2], c3 = b2p[l * 4 + 3];
    float o[8];
    o[0] = fmaf(a0.x, inv, c0.x); o[1] = fmaf(a0.y, inv, c0.y);
    o[2] = fmaf(a1.x, inv, c1.x); o[3] = fmaf(a1.y, inv, c1.y);
    o[4] = fmaf(a2.x, inv, c2.x); o[5] = fmaf(a2.y, inv, c2.y);
    o[6] = fmaf(a3.x, inv, c3.x); o[7] = fmaf(a3.y, inv, c3.y);
    uint4 ov;
    ov.x = (unsigned int)f2b(o[0]) | ((unsigned int)f2b(o[1]) << 16);
    ov.y = (unsigned int)f2b(o[2]) | ((unsigned int)f2b(o[3]) << 16);
    ov.z = (unsigned int)f2b(o[4]) | ((unsigned int)f2b(o[5]) << 16);
    ov.w = (unsigned int)f2b(o[6]) | ((unsigned int)f2b(o[7]) << 16);
    ((uint4*)haggB)[(size_t)w * 16 + l] = ov;

    // fused BN stats: reduce the wave's 4 nodes per channel, then block, then global
    float sst[8], qst[8];
#pragma unroll
    for (int k = 0; k < 8; k++) { sst[k] = o[k]; qst[k] = o[k] * o[k]; }
#pragma unroll
    for (int k = 0; k < 8; k++) {
        sst[k] += __shfl_xor(sst[k], 16, 64); sst[k] += __shfl_xor(sst[k], 32, 64);
        qst[k] += __shfl_xor(qst[k], 16, 64); qst[k] += __shfl_xor(qst[k], 32, 64);
    }
    int wv = threadIdx.x >> 6, ln = threadIdx.x & 63;
    if (ln < 16) {
#pragma unroll
        for (int k = 0; k < 8; k++) {
            lds_s[wv][8 * ln + k] = sst[k];
            lds_q[wv][8 * ln + k] = qst[k];
        }
    }
    __syncthreads();
    if (threadIdx.x < 128) {
        int c = threadIdx.x;
        float ss = lds_s[0][c] + lds_s[1][c] + lds_s[2][c] + lds_s[3][c];
        float qq = lds_q[0][c] + lds_q[1][c] + lds_q[2][c] + lds_q[3][c];
        atomicAdd(&gsum[c], ss);
        atomicAdd(&gsq[c], qq);
    }
}

// ---------------- output head: BN+ELU on bf16 in, in-block BN finalize ----------------
__global__ __launch_bounds__(256) void k_outgemm(const unsigned short* __restrict__ h,
                                                 const float* __restrict__ sums,
                                                 const float* __restrict__ sqs,
                                                 const float* __restrict__ gamma,
                                                 const float* __restrict__ beta,
                                                 const float* __restrict__ Wout,
                                                 const float* __restrict__ bout,
                                                 float* __restrict__ out, int n) {
    __shared__ float lwT[40][128];
    __shared__ float lh[64][132];
    __shared__ float lb[40];
    __shared__ float lsc[128], lsh[128];
    int t = threadIdx.x;
    if (t < 128) {
        float mu = sums[t] * (1.f / NNODES);
        float var = fmaxf(sqs[t] * (1.f / NNODES) - mu * mu, 0.f);
        float s = gamma[t] * rsqrtf(var + BNEPS);
        lsc[t] = s;
        lsh[t] = beta[t] - mu * s;
    }
    for (int idx = t; idx < 128 * 40; idx += 256) {
        int r = idx / 40, c = idx % 40;
        lwT[c][r] = Wout[idx];
    }
    if (t < 40) lb[t] = bout[t];
    __syncthreads();
    int n0 = blockIdx.x * 64;
    const uint4* hb4 = (const uint4*)h;
#pragma unroll
    for (int j = 0; j < 4; j++) {
        int idx = t + j * 256;
        int r = idx >> 4, seg = idx & 15;
        uint4 v = make_uint4(0, 0, 0, 0);
        if (n0 + r < n) v = hb4[(size_t)(n0 + r) * 16 + seg];
        float f[8];
        f[0] = blo2f(v.x); f[1] = bhi2f(v.x);
        f[2] = blo2f(v.y); f[3] = bhi2f(v.y);
        f[4] = blo2f(v.z); f[5] = bhi2f(v.z);
        f[6] = blo2f(v.w); f[7] = bhi2f(v.w);
#pragma unroll
        for (int k = 0; k < 8; k++) {
            int c = seg * 8 + k;
            float z = fmaf(f[k], lsc[c], lsh[c]);
            z = z > 0.f ? z : __expf(z) - 1.f;
            lh[r][c] = z;
        }
    }
    __syncthreads();
    int nl = t & 63, g = t >> 6;
    int row = n0 + nl;
    if (row >= n) return;
    float acc[10] = {};
    for (int k = 0; k < 128; k += 4) {
        float4 hv = *(const float4*)&lh[nl][k];
#pragma unroll
        for (int j = 0; j < 10; j++) {
            float4 wv = *(const float4*)&lwT[g * 10 + j][k];
            acc[j] += hv.x * wv.x + hv.y * wv.y + hv.z * wv.z + hv.w * wv.w;
        }
    }
#pragma unroll
    for (int j = 0; j < 10; j++)
        out[(size_t)row * 40 + g * 10 + j] = acc[j] + lb[g * 10 + j];
}

// ---------------- launch ----------------
extern "C" void kernel_launch(void* const* d_in, const int* in_sizes, int n_in,
                              void* d_out, int out_size, void* d_ws, size_t ws_size,
                              hipStream_t stream) {
    const float* x      = (const float*)d_in[0];
    const int*   ei     = (const int*)d_in[1];
    const float* W1     = (const float*)d_in[2];
    const float* a_src1 = (const float*)d_in[3];
    const float* a_dst1 = (const float*)d_in[4];
    const float* b1     = (const float*)d_in[5];
    const float* W2     = (const float*)d_in[6];
    const float* a_src2 = (const float*)d_in[7];
    const float* a_dst2 = (const float*)d_in[8];
    const float* b2     = (const float*)d_in[9];
    const float* gamma  = (const float*)d_in[10];
    const float* beta   = (const float*)d_in[11];
    const float* Wout   = (const float*)d_in[12];
    const float* bout   = (const float*)d_in[13];
    float* out = (float*)d_out;

    char* p = (char*)d_ws;
    auto alloc = [&](size_t bytes) -> void* {
        void* r = (void*)p;
        p += (bytes + 255) & ~(size_t)255;
        return r;
    };
    unsigned short* hB    = (unsigned short*)alloc((size_t)NNODES * 128 * 2);
    unsigned short* haggB = (unsigned short*)alloc((size_t)NNODES * 128 * 2);
    float* es     = (float*)alloc((size_t)NNODES * 4);
    float* ed     = (float*)alloc((size_t)NNODES * 4);
    int*   pairs  = (int*)alloc((size_t)ET * 4);
    int*   srcs   = (int*)alloc((size_t)ET * 4);
    int*   rowptr = (int*)alloc((size_t)(NNODES + 1) * 4);
    int*   perm   = (int*)alloc((size_t)NNODES * 4);
    int*   bcnt   = (int*)alloc(256 * 4);
    int*   bbase  = (int*)alloc(256 * 4);
    int*   bcur   = (int*)alloc(256 * 4);
    int*   dhist  = (int*)alloc(256 * 4);
    int*   dcur   = (int*)alloc(256 * 4);
    float* bnstat = (float*)alloc(4 * 128 * 4);
    unsigned short* WT1 = (unsigned short*)alloc(128 * 128 * 2);
    unsigned short* WT2 = (unsigned short*)alloc(128 * 128 * 2);
    int*   flag   = (int*)alloc(4);
    int*   done   = (int*)alloc(4);

    float* sum1 = bnstat, *sq1 = bnstat + 128, *sum2 = bnstat + 256, *sq2 = bnstat + 384;

    k_prep<<<64, 256, 0, stream>>>(W1, W2, WT1, WT2, ei, flag, bcnt, done, bnstat, dhist);
    k_bhist<<<NBLK_E, 256, 0, stream>>>(ei, flag, bcnt, done, bbase, bcur);
    k_bscatter<<<NBLK_E, 256, 0, stream>>>(ei, flag, bcur, pairs);
    k_bsort<<<NBUCK, 256, 0, stream>>>(pairs, bbase, rowptr, srcs, dhist);
    k_dscan<<<1, 256, 0, stream>>>(dhist, dcur);
    k_dperm<<<(NNODES + 255) / 256, 256, 0, stream>>>(rowptr, dcur, perm);

    const int GB = (NNODES + 63) / 64;            // 1563
    const int AB = NNODES / 16;                   // 6250 (16 nodes/block, exact)

    // ---- layer 1 ----
    k_gemm<false><<<GB, 256, 0, stream>>>(x, WT1, nullptr, nullptr, nullptr, nullptr,
                                          a_src1, a_dst1, es, ed, hB, NNODES);
    k_attn<<<AB, 256, 0, stream>>>(hB, srcs, rowptr, perm, es, ed, b1, haggB, sum1, sq1);

    // ---- layer 2 (BN+ELU finalized+fused in A-staging) ----
    k_gemm<true><<<GB, 256, 0, stream>>>(haggB, WT2, sum1, sq1, gamma, beta,
                                         a_src2, a_dst2, es, ed, hB, NNODES);
    k_attn<<<AB, 256, 0, stream>>>(hB, srcs, rowptr, perm, es, ed, b2, haggB, sum2, sq2);

    // ---- head (BN finalize + ELU fused into staging) ----
    k_outgemm<<<GB, 256, 0, stream>>>(haggB, sum2, sq2, gamma, beta, Wout, bout, out, NNODES);

    (void)in_sizes; (void)n_in; (void)out_size; (void)ws_size;
}

// Round 7
// 477.707 us; speedup vs baseline: 1.3834x; 1.3834x over previous
//
#include <hip/hip_runtime.h>

#define NNODES 100000
#define NEDGES 1600000
#define ET (NEDGES + NNODES)      // 1,700,000 incl. self loops
#define NBUCK 196                 // ceil(100000/512) buckets of 512 nodes
#define NEG 0.2f
#define BNEPS 1e-5f
#define EPB 4096                  // edges per block, bucket passes
#define NBLK_E ((ET + EPB - 1) / EPB)   // 416

typedef __attribute__((ext_vector_type(8))) short short8;
typedef __attribute__((ext_vector_type(4))) float floatx4;
typedef __attribute__((ext_vector_type(2))) float floatx2;

__device__ __forceinline__ unsigned short f2b(float x) {
    unsigned int u = __float_as_uint(x);
    u += 0x7fff + ((u >> 16) & 1);        // RNE
    return (unsigned short)(u >> 16);
}
__device__ __forceinline__ float b2f(unsigned short u) {
    return __uint_as_float(((unsigned int)u) << 16);
}
__device__ __forceinline__ float blo2f(unsigned int v) {
    return __uint_as_float(v << 16);
}
__device__ __forceinline__ float bhi2f(unsigned int v) {
    return __uint_as_float(v & 0xffff0000u);
}
__device__ __forceinline__ floatx2 u2f2(unsigned int v) {
    floatx2 r;
    r.x = __uint_as_float(v << 16);
    r.y = __uint_as_float(v & 0xffff0000u);
    return r;
}

// ---------------- edge decode (int32 vs int64 hedge) ----------------
__device__ __forceinline__ int edge_src(const int* ei, int e, int w64) {
    if (e >= NEDGES) return e - NEDGES;          // self loop
    return w64 ? ei[2 * e] : ei[e];
}
__device__ __forceinline__ int edge_dst(const int* ei, int e, int w64) {
    if (e >= NEDGES) return e - NEDGES;
    return w64 ? ei[2 * (NEDGES + e)] : ei[NEDGES + e];
}

// ---------------- prep: dtype detect + W transpose + scratch zeroing ----------------
__global__ void k_prep(const float* __restrict__ W1, const float* __restrict__ W2,
                       unsigned short* __restrict__ WT1, unsigned short* __restrict__ WT2,
                       const int* ei, int* flag, int* bcnt, int* done, float* bnstat) {
    int t = blockIdx.x * 256 + threadIdx.x;      // 16384 threads
    if (blockIdx.x == 0) {
        bcnt[threadIdx.x] = 0;
        if (threadIdx.x == 0) *done = 0;
        if (threadIdx.x == 1) {
            int is64 = 1;
            for (int j = 1; j < 16; j += 2)
                if (ei[j] != 0) is64 = 0;
            *flag = is64;
        }
    } else if (blockIdx.x == 1) {
        bnstat[threadIdx.x] = 0.f;
    } else if (blockIdx.x == 2) {
        bnstat[256 + threadIdx.x] = 0.f;
    }
    int k = t >> 7, n = t & 127;
    WT1[n * 128 + k] = f2b(W1[t]);
    WT2[n * 128 + k] = f2b(W2[t]);
}

// ---------------- CSR build pass A: bucket histogram (+inline scan, last block) ----
__global__ __launch_bounds__(256) void k_bhist(const int* __restrict__ ei,
                                               const int* flag, int* bcnt,
                                               int* done, int* bbase, int* bcur) {
    __shared__ int lc[256];
    __shared__ int lastf;
    int t = threadIdx.x;
    lc[t] = 0;
    __syncthreads();
    int w64 = *flag;
    int base = blockIdx.x * EPB;
    for (int j = 0; j < EPB / 512; j++) {
        int e = base + j * 512 + t * 2;          // 2 edges per thread
        if (e + 1 < NEDGES) {
            int d0, d1;
            if (w64) {
                int4 dv = *(const int4*)&ei[2 * (NEDGES + e)];
                d0 = dv.x; d1 = dv.z;
            } else {
                int2 dv = *(const int2*)&ei[NEDGES + e];
                d0 = dv.x; d1 = dv.y;
            }
            atomicAdd(&lc[d0 >> 9], 1);
            atomicAdd(&lc[d1 >> 9], 1);
        } else {
            for (int k = 0; k < 2; k++) {
                int ee = e + k;
                if (ee < ET) atomicAdd(&lc[edge_dst(ei, ee, w64) >> 9], 1);
            }
        }
    }
    __syncthreads();
    if (t < NBUCK && lc[t]) atomicAdd(&bcnt[t], lc[t]);
    __threadfence();
    __syncthreads();
    if (t == 0) lastf = (atomicAdd(done, 1) == gridDim.x - 1) ? 1 : 0;
    __syncthreads();
    if (!lastf) return;
    // inline 196-bucket exclusive scan
    int v = (t < NBUCK) ? atomicAdd(&bcnt[t], 0) : 0;
    __syncthreads();
    lc[t] = v;
    __syncthreads();
    for (int off = 1; off < 256; off <<= 1) {
        int add = (t >= off) ? lc[t - off] : 0;
        __syncthreads();
        lc[t] += add;
        __syncthreads();
    }
    int excl = lc[t] - v;
    if (t < NBUCK) { bbase[t] = excl; bcur[t] = excl; }
    if (t == NBUCK - 1) bbase[NBUCK] = excl + v;
}

// ---------------- pass C: partition packed pairs into bucket regions ----------------
// pairs packed: (src << 9) | (dst & 511); src < 2^17
__global__ __launch_bounds__(256) void k_bscatter(const int* __restrict__ ei,
                                                  const int* flag, int* bcur,
                                                  int* __restrict__ pairs) {
    __shared__ int lc[256];
    __shared__ int lbase[256];
    int t = threadIdx.x;
    lc[t] = 0;
    __syncthreads();
    int w64 = *flag;
    int base = blockIdx.x * EPB;
    for (int j = 0; j < EPB / 512; j++) {
        int e = base + j * 512 + t * 2;
        if (e + 1 < NEDGES) {
            int d0, d1;
            if (w64) {
                int4 dv = *(const int4*)&ei[2 * (NEDGES + e)];
                d0 = dv.x; d1 = dv.z;
            } else {
                int2 dv = *(const int2*)&ei[NEDGES + e];
                d0 = dv.x; d1 = dv.y;
            }
            atomicAdd(&lc[d0 >> 9], 1);
            atomicAdd(&lc[d1 >> 9], 1);
        } else {
            for (int k = 0; k < 2; k++) {
                int ee = e + k;
                if (ee < ET) atomicAdd(&lc[edge_dst(ei, ee, w64) >> 9], 1);
            }
        }
    }
    __syncthreads();
    if (t < NBUCK && lc[t]) lbase[t] = atomicAdd(&bcur[t], lc[t]);
    __syncthreads();
    for (int j = 0; j < EPB / 512; j++) {
        int e = base + j * 512 + t * 2;
        if (e + 1 < NEDGES) {
            int s0, s1, d0, d1;
            if (w64) {
                int4 sv = *(const int4*)&ei[2 * e];
                int4 dv = *(const int4*)&ei[2 * (NEDGES + e)];
                s0 = sv.x; s1 = sv.z; d0 = dv.x; d1 = dv.z;
            } else {
                int2 sv = *(const int2*)&ei[e];
                int2 dv = *(const int2*)&ei[NEDGES + e];
                s0 = sv.x; s1 = sv.y; d0 = dv.x; d1 = dv.y;
            }
            int p0 = atomicAdd(&lbase[d0 >> 9], 1);
            pairs[p0] = (s0 << 9) | (d0 & 511);
            int p1 = atomicAdd(&lbase[d1 >> 9], 1);
            pairs[p1] = (s1 << 9) | (d1 & 511);
        } else {
            for (int k = 0; k < 2; k++) {
                int ee = e + k;
                if (ee < ET) {
                    int src = edge_src(ei, ee, w64);
                    int dst = edge_dst(ei, ee, w64);
                    int pos = atomicAdd(&lbase[dst >> 9], 1);
                    pairs[pos] = (src << 9) | (dst & 511);
                }
            }
        }
    }
}

// ---------------- pass D: per-bucket counting sort -> rowptr + srcs ----------------
__global__ __launch_bounds__(256) void k_bsort(const int* __restrict__ pairs,
                                               const int* __restrict__ bbase,
                                               int* __restrict__ rowptr,
                                               int* __restrict__ srcs) {
    __shared__ int ncnt[512];
    __shared__ int nbase[512];
    __shared__ int stmp[256];
    int b = blockIdx.x, t = threadIdx.x;
    ncnt[t] = 0; ncnt[t + 256] = 0;
    __syncthreads();
    int s0 = bbase[b], s1 = bbase[b + 1];
    for (int i = s0 + t; i < s1; i += 256)
        atomicAdd(&ncnt[pairs[i] & 511], 1);
    __syncthreads();
    int c0 = ncnt[2 * t], c1 = ncnt[2 * t + 1];
    int s = c0 + c1;
    stmp[t] = s;
    __syncthreads();
    for (int off = 1; off < 256; off <<= 1) {
        int add = (t >= off) ? stmp[t - off] : 0;
        __syncthreads();
        stmp[t] += add;
        __syncthreads();
    }
    int excl = stmp[t] - s;
    nbase[2 * t] = excl;
    nbase[2 * t + 1] = excl + c0;
    __syncthreads();
    for (int l = t; l < 512; l += 256) {
        int node = b * 512 + l;
        if (node <= NNODES) rowptr[node] = s0 + nbase[l];
        ncnt[l] = nbase[l];            // becomes cursor
    }
    __syncthreads();
    for (int i = s0 + t; i < s1; i += 256) {
        int pr = pairs[i];
        int off = atomicAdd(&ncnt[pr & 511], 1);
        srcs[s0 + off] = ((unsigned int)pr) >> 9;
    }
}

// ---------------- MFMA GEMM (+in-block BN/ELU on bf16 A) + fused scores ----------------
template<bool BN>
__global__ __launch_bounds__(256) void k_gemm(const void* __restrict__ Ain,
        const unsigned short* __restrict__ WTg,
        const float* __restrict__ sums, const float* __restrict__ sqs,
        const float* __restrict__ gamma, const float* __restrict__ beta,
        const float* __restrict__ a_s, const float* __restrict__ a_d,
        float* __restrict__ es, float* __restrict__ ed,
        unsigned short* __restrict__ hB, int n) {
    __shared__ unsigned short lA[64][136];
    __shared__ unsigned short lW[128][136];
    __shared__ float las[128], lad[128];
    __shared__ float lsc[128], lsh[128];
    int t = threadIdx.x;
    int row0 = blockIdx.x * 64;
    if (t < 128) { las[t] = a_s[t]; lad[t] = a_d[t]; }
    if (BN && t < 128) {
        float mu = sums[t] * (1.f / NNODES);
        float var = fmaxf(sqs[t] * (1.f / NNODES) - mu * mu, 0.f);
        float s = gamma[t] * rsqrtf(var + BNEPS);
        lsc[t] = s;
        lsh[t] = beta[t] - mu * s;
    }

    const uint4* wt4 = (const uint4*)WTg;
#pragma unroll
    for (int j = 0; j < 8; j++) {
        int idx = t + j * 256;
        *(uint4*)&lW[idx >> 4][(idx & 15) * 8] = wt4[idx];
    }
    if (BN) __syncthreads();   // lsc/lsh visible before A staging

    if (BN) {
        const uint4* Ab = (const uint4*)Ain;   // bf16 rows, 16 uint4 each
#pragma unroll
        for (int j = 0; j < 4; j++) {
            int idx = t + j * 256;
            int r = idx >> 4, seg = idx & 15;
            uint4 v = make_uint4(0, 0, 0, 0);
            if (row0 + r < n) v = Ab[(size_t)(row0 + r) * 16 + seg];
            float f[8];
            f[0] = blo2f(v.x); f[1] = bhi2f(v.x);
            f[2] = blo2f(v.y); f[3] = bhi2f(v.y);
            f[4] = blo2f(v.z); f[5] = bhi2f(v.z);
            f[6] = blo2f(v.w); f[7] = bhi2f(v.w);
            ushort4 u0, u1;
            unsigned short us[8];
#pragma unroll
            for (int k = 0; k < 8; k++) {
                int c = seg * 8 + k;
                float z = fmaf(f[k], lsc[c], lsh[c]);
                z = z > 0.f ? z : __expf(z) - 1.f;
                us[k] = f2b(z);
            }
            u0.x = us[0]; u0.y = us[1]; u0.z = us[2]; u0.w = us[3];
            u1.x = us[4]; u1.y = us[5]; u1.z = us[6]; u1.w = us[7];
            *(ushort4*)&lA[r][seg * 8] = u0;
            *(ushort4*)&lA[r][seg * 8 + 4] = u1;
        }
    } else {
        const float* Af = (const float*)Ain;
#pragma unroll
        for (int j = 0; j < 8; j++) {
            int idx = t + j * 256;
            int r = idx >> 5, c4 = idx & 31;
            float4 v = make_float4(0.f, 0.f, 0.f, 0.f);
            if (row0 + r < n) v = ((const float4*)Af)[(size_t)(row0 + r) * 32 + c4];
            ushort4 u;
            u.x = f2b(v.x); u.y = f2b(v.y); u.z = f2b(v.z); u.w = f2b(v.w);
            *(ushort4*)&lA[r][c4 * 4] = u;
        }
    }
    __syncthreads();

    int w = t >> 6, lane = t & 63;
    int m = lane & 15, q = lane >> 4;
    int arow = w * 16 + m;
    floatx4 acc[8];
#pragma unroll
    for (int ct = 0; ct < 8; ct++) acc[ct] = (floatx4)0.0f;

#pragma unroll
    for (int kt = 0; kt < 4; kt++) {
        int kb = kt * 32 + q * 8;
        short8 af = *(const short8*)&lA[arow][kb];
#pragma unroll
        for (int ct = 0; ct < 8; ct++) {
            short8 bf = *(const short8*)&lW[ct * 16 + m][kb];
            acc[ct] = __builtin_amdgcn_mfma_f32_16x16x32_bf16(af, bf, acc[ct], 0, 0, 0);
        }
    }

    __syncthreads();   // done reading lA as input; about to overwrite with C tile
#pragma unroll
    for (int ct = 0; ct < 8; ct++)
#pragma unroll
        for (int r = 0; r < 4; r++)
            lA[w * 16 + q * 4 + r][ct * 16 + m] = f2b(acc[ct][r]);
#pragma unroll
    for (int j = 0; j < 4; j++) {
        int idx = lane + j * 64;
        int r = idx >> 4, seg = idx & 15;
        int grow = row0 + w * 16 + r;
        if (grow < n) {
            uint4 v = *(const uint4*)&lA[w * 16 + r][seg * 8];
            ((uint4*)hB)[(size_t)grow * 16 + seg] = v;
        }
    }
    __syncthreads();
    // fused attention scores: 4 threads per row, 32 chans each
    int r = t >> 2, q4 = t & 3;
    float s1 = 0.f, s2 = 0.f;
#pragma unroll
    for (int k = 0; k < 32; k++) {
        int c = q4 * 32 + k;
        float v = b2f(lA[r][c]);
        s1 += v * las[c];
        s2 += v * lad[c];
    }
    s1 += __shfl_xor(s1, 1, 64); s1 += __shfl_xor(s1, 2, 64);
    s2 += __shfl_xor(s2, 1, 64); s2 += __shfl_xor(s2, 2, 64);
    if (q4 == 0 && row0 + r < n) { es[row0 + r] = s1; ed[row0 + r] = s2; }
}

// ---------------- fused softmax + weighted gather (half-wave per node) ----------
// one pass: no max subtraction (scores bounded |e| << 88, exp safe in fp32;
// alpha = p/den is shift-invariant so result identical)
__global__ __launch_bounds__(256) void k_attn(const unsigned short* __restrict__ hB,
                                              const int* __restrict__ srcs,
                                              const int* __restrict__ rowptr,
                                              const float* __restrict__ es,
                                              const float* __restrict__ ed,
                                              const float* __restrict__ bias,
                                              unsigned short* __restrict__ haggB, int n) {
    int w = (blockIdx.x * 256 + threadIdx.x) >> 5;   // node per half-wave
    if (w >= n) return;
    int lane32 = threadIdx.x & 31;
    int g = lane32 >> 4, l16 = lane32 & 15;
    int base = threadIdx.x & 32;                     // this half's lane offset in wave
    int start = rowptr[w], end = rowptr[w + 1];
    float edv = ed[w];
    const uint4* hp4 = (const uint4*)hB;
    floatx2 a0 = {0.f, 0.f}, a1 = {0.f, 0.f}, a2 = {0.f, 0.f}, a3 = {0.f, 0.f};
    float den = 0.f;

    for (int chunk = start; chunk < end; chunk += 32) {
        int i = chunk + lane32;
        int sv = 0; float pv = 0.f;
        if (i < end) {
            sv = srcs[i];
            float e = es[sv] + edv;
            e = e > 0.f ? e : NEG * e;
            pv = __expf(e);
            den += pv;
        }
        int cnt = min(32, end - chunk);
        for (int j = 0; j < cnt; j += 4) {           // 2 groups x 2 edges per iter
            int   s0 = __shfl(sv, base + j + g, 64);
            float p0 = __shfl(pv, base + j + g, 64);
            int   s1 = __shfl(sv, base + j + 2 + g, 64);
            float p1 = __shfl(pv, base + j + 2 + g, 64);
            if (p0 != 0.f) {
                uint4 h0 = hp4[(size_t)s0 * 16 + l16];
                floatx2 P = {p0, p0};
                a0 += P * u2f2(h0.x); a1 += P * u2f2(h0.y);
                a2 += P * u2f2(h0.z); a3 += P * u2f2(h0.w);
            }
            if (p1 != 0.f) {
                uint4 h1 = hp4[(size_t)s1 * 16 + l16];
                floatx2 P = {p1, p1};
                a0 += P * u2f2(h1.x); a1 += P * u2f2(h1.y);
                a2 += P * u2f2(h1.z); a3 += P * u2f2(h1.w);
            }
        }
    }
    den += __shfl_xor(den, 1, 64);  den += __shfl_xor(den, 2, 64);
    den += __shfl_xor(den, 4, 64);  den += __shfl_xor(den, 8, 64);
    den += __shfl_xor(den, 16, 64);
    a0.x += __shfl_xor(a0.x, 16, 64); a0.y += __shfl_xor(a0.y, 16, 64);
    a1.x += __shfl_xor(a1.x, 16, 64); a1.y += __shfl_xor(a1.y, 16, 64);
    a2.x += __shfl_xor(a2.x, 16, 64); a2.y += __shfl_xor(a2.y, 16, 64);
    a3.x += __shfl_xor(a3.x, 16, 64); a3.y += __shfl_xor(a3.y, 16, 64);
    if (g == 0) {
        float inv = 1.f / den;                       // den > 0: self loop guaranteed
        const float2* b2p = (const float2*)bias;
        float2 c0 = b2p[l16 * 4 + 0], c1 = b2p[l16 * 4 + 1];
        float2 c2 = b2p[l16 * 4 + 2], c3 = b2p[l16 * 4 + 3];
        uint4 o;
        o.x = (unsigned int)f2b(fmaf(a0.x, inv, c0.x)) |
              ((unsigned int)f2b(fmaf(a0.y, inv, c0.y)) << 16);
        o.y = (unsigned int)f2b(fmaf(a1.x, inv, c1.x)) |
              ((unsigned int)f2b(fmaf(a1.y, inv, c1.y)) << 16);
        o.z = (unsigned int)f2b(fmaf(a2.x, inv, c2.x)) |
              ((unsigned int)f2b(fmaf(a2.y, inv, c2.y)) << 16);
        o.w = (unsigned int)f2b(fmaf(a3.x, inv, c3.x)) |
              ((unsigned int)f2b(fmaf(a3.y, inv, c3.y)) << 16);
        ((uint4*)haggB)[(size_t)w * 16 + l16] = o;
    }
}

// ---------------- BatchNorm stats from bf16 hagg ----------------
__global__ __launch_bounds__(256) void k_bnstats(const unsigned short* __restrict__ hin,
                                                 float* sums, float* sqs, int n) {
    __shared__ float red[4][256];
    int t = threadIdx.x;
    int c2 = t & 63, quarter = t >> 6;
    int r0 = blockIdx.x * 512;
    int rend = min(r0 + 512, n);
    const unsigned int* hp = (const unsigned int*)hin;
    float s0 = 0.f, q0 = 0.f, s1 = 0.f, q1 = 0.f;
    for (int r = r0 + quarter; r < rend; r += 4) {
        unsigned int v = hp[(size_t)r * 64 + c2];
        float a = blo2f(v), b = bhi2f(v);
        s0 += a; q0 += a * a;
        s1 += b; q1 += b * b;
    }
    *(float4*)&red[quarter][c2 * 4] = make_float4(s0, q0, s1, q1);
    __syncthreads();
    float v = red[0][t] + red[1][t] + red[2][t] + red[3][t];
    int c2i = t >> 2, k = t & 3;
    int ch = c2i * 2 + (k >> 1);
    if (k & 1) atomicAdd(&sqs[ch], v);
    else       atomicAdd(&sums[ch], v);
}

// ---------------- output head: BN+ELU on bf16 in, in-block BN finalize ----------------
__global__ __launch_bounds__(256) void k_outgemm(const unsigned short* __restrict__ h,
                                                 const float* __restrict__ sums,
                                                 const float* __restrict__ sqs,
                                                 const float* __restrict__ gamma,
                                                 const float* __restrict__ beta,
                                                 const float* __restrict__ Wout,
                                                 const float* __restrict__ bout,
                                                 float* __restrict__ out, int n) {
    __shared__ float lwT[40][128];
    __shared__ float lh[64][132];
    __shared__ float lb[40];
    __shared__ float lsc[128], lsh[128];
    int t = threadIdx.x;
    if (t < 128) {
        float mu = sums[t] * (1.f / NNODES);
        float var = fmaxf(sqs[t] * (1.f / NNODES) - mu * mu, 0.f);
        float s = gamma[t] * rsqrtf(var + BNEPS);
        lsc[t] = s;
        lsh[t] = beta[t] - mu * s;
    }
    for (int idx = t; idx < 128 * 40; idx += 256) {
        int r = idx / 40, c = idx % 40;
        lwT[c][r] = Wout[idx];
    }
    if (t < 40) lb[t] = bout[t];
    __syncthreads();
    int n0 = blockIdx.x * 64;
    const uint4* hb4 = (const uint4*)h;
#pragma unroll
    for (int j = 0; j < 4; j++) {
        int idx = t + j * 256;
        int r = idx >> 4, seg = idx & 15;
        uint4 v = make_uint4(0, 0, 0, 0);
        if (n0 + r < n) v = hb4[(size_t)(n0 + r) * 16 + seg];
        float f[8];
        f[0] = blo2f(v.x); f[1] = bhi2f(v.x);
        f[2] = blo2f(v.y); f[3] = bhi2f(v.y);
        f[4] = blo2f(v.z); f[5] = bhi2f(v.z);
        f[6] = blo2f(v.w); f[7] = bhi2f(v.w);
#pragma unroll
        for (int k = 0; k < 8; k++) {
            int c = seg * 8 + k;
            float z = fmaf(f[k], lsc[c], lsh[c]);
            z = z > 0.f ? z : __expf(z) - 1.f;
            lh[r][c] = z;
        }
    }
    __syncthreads();
    int nl = t & 63, g = t >> 6;
    int row = n0 + nl;
    if (row >= n) return;
    float acc[10] = {};
    for (int k = 0; k < 128; k += 4) {
        float4 hv = *(const float4*)&lh[nl][k];
#pragma unroll
        for (int j = 0; j < 10; j++) {
            float4 wv = *(const float4*)&lwT[g * 10 + j][k];
            acc[j] += hv.x * wv.x + hv.y * wv.y + hv.z * wv.z + hv.w * wv.w;
        }
    }
#pragma unroll
    for (int j = 0; j < 10; j++)
        out[(size_t)row * 40 + g * 10 + j] = acc[j] + lb[g * 10 + j];
}

// ---------------- launch ----------------
extern "C" void kernel_launch(void* const* d_in, const int* in_sizes, int n_in,
                              void* d_out, int out_size, void* d_ws, size_t ws_size,
                              hipStream_t stream) {
    const float* x      = (const float*)d_in[0];
    const int*   ei     = (const int*)d_in[1];
    const float* W1     = (const float*)d_in[2];
    const float* a_src1 = (const float*)d_in[3];
    const float* a_dst1 = (const float*)d_in[4];
    const float* b1     = (const float*)d_in[5];
    const float* W2     = (const float*)d_in[6];
    const float* a_src2 = (const float*)d_in[7];
    const float* a_dst2 = (const float*)d_in[8];
    const float* b2     = (const float*)d_in[9];
    const float* gamma  = (const float*)d_in[10];
    const float* beta   = (const float*)d_in[11];
    const float* Wout   = (const float*)d_in[12];
    const float* bout   = (const float*)d_in[13];
    float* out = (float*)d_out;

    char* p = (char*)d_ws;
    auto alloc = [&](size_t bytes) -> void* {
        void* r = (void*)p;
        p += (bytes + 255) & ~(size_t)255;
        return r;
    };
    unsigned short* hB    = (unsigned short*)alloc((size_t)NNODES * 128 * 2);
    unsigned short* haggB = (unsigned short*)alloc((size_t)NNODES * 128 * 2);
    float* es     = (float*)alloc((size_t)NNODES * 4);
    float* ed     = (float*)alloc((size_t)NNODES * 4);
    int*   pairs  = (int*)alloc((size_t)ET * 4);
    int*   srcs   = (int*)alloc((size_t)ET * 4);
    int*   rowptr = (int*)alloc((size_t)(NNODES + 1) * 4);
    int*   bcnt   = (int*)alloc(256 * 4);
    int*   bbase  = (int*)alloc(256 * 4);
    int*   bcur   = (int*)alloc(256 * 4);
    float* bnstat = (float*)alloc(4 * 128 * 4);
    unsigned short* WT1 = (unsigned short*)alloc(128 * 128 * 2);
    unsigned short* WT2 = (unsigned short*)alloc(128 * 128 * 2);
    int*   flag   = (int*)alloc(4);
    int*   done   = (int*)alloc(4);

    float* sum1 = bnstat, *sq1 = bnstat + 128, *sum2 = bnstat + 256, *sq2 = bnstat + 384;

    k_prep<<<64, 256, 0, stream>>>(W1, W2, WT1, WT2, ei, flag, bcnt, done, bnstat);
    k_bhist<<<NBLK_E, 256, 0, stream>>>(ei, flag, bcnt, done, bbase, bcur);
    k_bscatter<<<NBLK_E, 256, 0, stream>>>(ei, flag, bcur, pairs);
    k_bsort<<<NBUCK, 256, 0, stream>>>(pairs, bbase, rowptr, srcs);

    const int GB = (NNODES + 63) / 64;            // 1563
    const int AB = NNODES / 8;                    // 12500 (8 nodes/block, exact)
    const int SB = (NNODES + 511) / 512;          // 196

    // ---- layer 1 ----
    k_gemm<false><<<GB, 256, 0, stream>>>(x, WT1, nullptr, nullptr, nullptr, nullptr,
                                          a_src1, a_dst1, es, ed, hB, NNODES);
    k_attn<<<AB, 256, 0, stream>>>(hB, srcs, rowptr, es, ed, b1, haggB, NNODES);
    k_bnstats<<<SB, 256, 0, stream>>>(haggB, sum1, sq1, NNODES);

    // ---- layer 2 (BN+ELU finalized+fused in A-staging) ----
    k_gemm<true><<<GB, 256, 0, stream>>>(haggB, WT2, sum1, sq1, gamma, beta,
                                         a_src2, a_dst2, es, ed, hB, NNODES);
    k_attn<<<AB, 256, 0, stream>>>(hB, srcs, rowptr, es, ed, b2, haggB, NNODES);
    k_bnstats<<<SB, 256, 0, stream>>>(haggB, sum2, sq2, NNODES);

    // ---- head (BN finalize + ELU fused into staging) ----
    k_outgemm<<<GB, 256, 0, stream>>>(haggB, sum2, sq2, gamma, beta, Wout, bout, out, NNODES);

    (void)in_sizes; (void)n_in; (void)out_size; (void)ws_size;
}

// Round 8
// 458.807 us; speedup vs baseline: 1.4404x; 1.0412x over previous
//
#include <hip/hip_runtime.h>

#define NNODES 100000
#define NEDGES 1600000
#define ET (NEDGES + NNODES)      // 1,700,000 incl. self loops
#define NBUCK 782                 // ceil(100000/128) buckets of 128 nodes
#define NEG 0.2f
#define BNEPS 1e-5f
#define EPB 4096                  // edges per block, bucket passes
#define NBLK_E ((ET + EPB - 1) / EPB)   // 416

typedef __attribute__((ext_vector_type(8))) short short8;
typedef __attribute__((ext_vector_type(4))) float floatx4;
typedef __attribute__((ext_vector_type(2))) float floatx2;

__device__ __forceinline__ unsigned short f2b(float x) {
    unsigned int u = __float_as_uint(x);
    u += 0x7fff + ((u >> 16) & 1);        // RNE
    return (unsigned short)(u >> 16);
}
__device__ __forceinline__ float b2f(unsigned short u) {
    return __uint_as_float(((unsigned int)u) << 16);
}
__device__ __forceinline__ float blo2f(unsigned int v) {
    return __uint_as_float(v << 16);
}
__device__ __forceinline__ float bhi2f(unsigned int v) {
    return __uint_as_float(v & 0xffff0000u);
}
__device__ __forceinline__ floatx2 u2f2(unsigned int v) {
    floatx2 r;
    r.x = __uint_as_float(v << 16);
    r.y = __uint_as_float(v & 0xffff0000u);
    return r;
}

// ---------------- edge decode (int32 vs int64 hedge) ----------------
__device__ __forceinline__ int edge_src(const int* ei, int e, int w64) {
    if (e >= NEDGES) return e - NEDGES;          // self loop
    return w64 ? ei[2 * e] : ei[e];
}
__device__ __forceinline__ int edge_dst(const int* ei, int e, int w64) {
    if (e >= NEDGES) return e - NEDGES;
    return w64 ? ei[2 * (NEDGES + e)] : ei[NEDGES + e];
}

// ---------------- prep: dtype detect + W transpose + scratch zeroing ----------------
__global__ void k_prep(const float* __restrict__ W1, const float* __restrict__ W2,
                       unsigned short* __restrict__ WT1, unsigned short* __restrict__ WT2,
                       const int* ei, int* flag, int* bcnt, int* done, float* bnstat) {
    int t = blockIdx.x * 256 + threadIdx.x;      // 16384 threads
    if (t < 800) bcnt[t] = 0;                    // blocks 0..3 cover bucket counts
    if (blockIdx.x == 4) {
        bnstat[threadIdx.x] = 0.f;
    } else if (blockIdx.x == 5) {
        bnstat[256 + threadIdx.x] = 0.f;
    }
    if (t == 0) *done = 0;
    if (t == 1) {
        int is64 = 1;
        for (int j = 1; j < 16; j += 2)
            if (ei[j] != 0) is64 = 0;
        *flag = is64;
    }
    int k = t >> 7, n = t & 127;
    WT1[n * 128 + k] = f2b(W1[t]);
    WT2[n * 128 + k] = f2b(W2[t]);
}

// ---------------- CSR build pass A: bucket histogram (+inline scan, last block) ----
__global__ __launch_bounds__(256) void k_bhist(const int* __restrict__ ei,
                                               const int* flag, int* bcnt,
                                               int* done, int* bbase, int* bcur) {
    __shared__ int lc[784];
    __shared__ int sh[256];
    __shared__ int lastf;
    int t = threadIdx.x;
    for (int i = t; i < NBUCK; i += 256) lc[i] = 0;
    __syncthreads();
    int w64 = *flag;
    int base = blockIdx.x * EPB;
    for (int j = 0; j < EPB / 512; j++) {
        int e = base + j * 512 + t * 2;          // 2 edges per thread
        if (e + 1 < NEDGES) {
            int d0, d1;
            if (w64) {
                int4 dv = *(const int4*)&ei[2 * (NEDGES + e)];
                d0 = dv.x; d1 = dv.z;
            } else {
                int2 dv = *(const int2*)&ei[NEDGES + e];
                d0 = dv.x; d1 = dv.y;
            }
            atomicAdd(&lc[d0 >> 7], 1);
            atomicAdd(&lc[d1 >> 7], 1);
        } else {
            for (int k = 0; k < 2; k++) {
                int ee = e + k;
                if (ee < ET) atomicAdd(&lc[edge_dst(ei, ee, w64) >> 7], 1);
            }
        }
    }
    __syncthreads();
    for (int i = t; i < NBUCK; i += 256)
        if (lc[i]) atomicAdd(&bcnt[i], lc[i]);
    __threadfence();
    __syncthreads();
    if (t == 0) lastf = (atomicAdd(done, 1) == gridDim.x - 1) ? 1 : 0;
    __syncthreads();
    if (!lastf) return;
    // inline 782-bucket exclusive scan (4 per thread)
    int vals[4], pre[4], sum = 0;
#pragma unroll
    for (int i = 0; i < 4; i++) {
        int id = t * 4 + i;
        int v = (id < NBUCK) ? atomicAdd(&bcnt[id], 0) : 0;
        pre[i] = sum; vals[i] = v; sum += v;
    }
    sh[t] = sum;
    __syncthreads();
    for (int off = 1; off < 256; off <<= 1) {
        int add = (t >= off) ? sh[t - off] : 0;
        __syncthreads();
        sh[t] += add;
        __syncthreads();
    }
    int excl = sh[t] - sum;
#pragma unroll
    for (int i = 0; i < 4; i++) {
        int id = t * 4 + i;
        if (id < NBUCK) { bbase[id] = excl + pre[i]; bcur[id] = excl + pre[i]; }
    }
    if (t == 255) bbase[NBUCK] = sh[255];
    (void)vals;
}

// ---------------- pass C: partition packed pairs into bucket regions ----------------
// pairs packed: (src << 7) | (dst & 127); src < 2^17
__global__ __launch_bounds__(256) void k_bscatter(const int* __restrict__ ei,
                                                  const int* flag, int* bcur,
                                                  int* __restrict__ pairs) {
    __shared__ int lc[784];
    __shared__ int lbase[784];
    int t = threadIdx.x;
    for (int i = t; i < NBUCK; i += 256) lc[i] = 0;
    __syncthreads();
    int w64 = *flag;
    int base = blockIdx.x * EPB;
    for (int j = 0; j < EPB / 512; j++) {
        int e = base + j * 512 + t * 2;
        if (e + 1 < NEDGES) {
            int d0, d1;
            if (w64) {
                int4 dv = *(const int4*)&ei[2 * (NEDGES + e)];
                d0 = dv.x; d1 = dv.z;
            } else {
                int2 dv = *(const int2*)&ei[NEDGES + e];
                d0 = dv.x; d1 = dv.y;
            }
            atomicAdd(&lc[d0 >> 7], 1);
            atomicAdd(&lc[d1 >> 7], 1);
        } else {
            for (int k = 0; k < 2; k++) {
                int ee = e + k;
                if (ee < ET) atomicAdd(&lc[edge_dst(ei, ee, w64) >> 7], 1);
            }
        }
    }
    __syncthreads();
    for (int i = t; i < NBUCK; i += 256)
        if (lc[i]) lbase[i] = atomicAdd(&bcur[i], lc[i]);
    __syncthreads();
    for (int j = 0; j < EPB / 512; j++) {
        int e = base + j * 512 + t * 2;
        if (e + 1 < NEDGES) {
            int s0, s1, d0, d1;
            if (w64) {
                int4 sv = *(const int4*)&ei[2 * e];
                int4 dv = *(const int4*)&ei[2 * (NEDGES + e)];
                s0 = sv.x; s1 = sv.z; d0 = dv.x; d1 = dv.z;
            } else {
                int2 sv = *(const int2*)&ei[e];
                int2 dv = *(const int2*)&ei[NEDGES + e];
                s0 = sv.x; s1 = sv.y; d0 = dv.x; d1 = dv.y;
            }
            int p0 = atomicAdd(&lbase[d0 >> 7], 1);
            pairs[p0] = (s0 << 7) | (d0 & 127);
            int p1 = atomicAdd(&lbase[d1 >> 7], 1);
            pairs[p1] = (s1 << 7) | (d1 & 127);
        } else {
            for (int k = 0; k < 2; k++) {
                int ee = e + k;
                if (ee < ET) {
                    int src = edge_src(ei, ee, w64);
                    int dst = edge_dst(ei, ee, w64);
                    int pos = atomicAdd(&lbase[dst >> 7], 1);
                    pairs[pos] = (src << 7) | (dst & 127);
                }
            }
        }
    }
}

// ---------------- pass D: per-bucket counting sort -> rowptr + srcs ----------------
__global__ __launch_bounds__(256) void k_bsort(const int* __restrict__ pairs,
                                               const int* __restrict__ bbase,
                                               int* __restrict__ rowptr,
                                               int* __restrict__ srcs) {
    __shared__ int ncnt[128];
    __shared__ int nbase[128];
    __shared__ int sscan[128];
    int b = blockIdx.x, t = threadIdx.x;
    if (t < 128) ncnt[t] = 0;
    __syncthreads();
    int s0 = bbase[b], s1 = bbase[b + 1];
    for (int i = s0 + t; i < s1; i += 256)
        atomicAdd(&ncnt[pairs[i] & 127], 1);
    __syncthreads();
    int v = (t < 128) ? ncnt[t] : 0;
    if (t < 128) sscan[t] = v;
    __syncthreads();
    for (int off = 1; off < 128; off <<= 1) {
        int add = (t < 128 && t >= off) ? sscan[t - off] : 0;
        __syncthreads();
        if (t < 128) sscan[t] += add;
        __syncthreads();
    }
    if (t < 128) {
        int excl = sscan[t] - v;
        nbase[t] = excl;
        int node = b * 128 + t;
        if (node <= NNODES) rowptr[node] = s0 + excl;
    }
    __syncthreads();
    if (t < 128) ncnt[t] = nbase[t];   // cursor
    __syncthreads();
    for (int i = s0 + t; i < s1; i += 256) {
        int pr = pairs[i];
        int off = atomicAdd(&ncnt[pr & 127], 1);
        srcs[s0 + off] = ((unsigned int)pr) >> 7;
    }
}

// ---------------- MFMA GEMM, 128-row tile (+BN/ELU on bf16 A) + fused scores --------
template<bool BN>
__global__ __launch_bounds__(256) void k_gemm(const void* __restrict__ Ain,
        const unsigned short* __restrict__ WTg,
        const float* __restrict__ sums, const float* __restrict__ sqs,
        const float* __restrict__ gamma, const float* __restrict__ beta,
        const float* __restrict__ a_s, const float* __restrict__ a_d,
        float* __restrict__ es, float* __restrict__ ed,
        unsigned short* __restrict__ hB, int n) {
    __shared__ unsigned short lA[128][136];
    __shared__ unsigned short lW[128][136];
    __shared__ float las[128], lad[128];
    __shared__ float lsc[128], lsh[128];
    int t = threadIdx.x;
    int row0 = blockIdx.x * 128;
    if (t < 128) { las[t] = a_s[t]; lad[t] = a_d[t]; }
    if (BN && t < 128) {
        float mu = sums[t] * (1.f / NNODES);
        float var = fmaxf(sqs[t] * (1.f / NNODES) - mu * mu, 0.f);
        float s = gamma[t] * rsqrtf(var + BNEPS);
        lsc[t] = s;
        lsh[t] = beta[t] - mu * s;
    }

    const uint4* wt4 = (const uint4*)WTg;
#pragma unroll
    for (int j = 0; j < 8; j++) {
        int idx = t + j * 256;
        *(uint4*)&lW[idx >> 4][(idx & 15) * 8] = wt4[idx];
    }
    if (BN) __syncthreads();   // lsc/lsh visible before A staging

    if (BN) {
        const uint4* Ab = (const uint4*)Ain;   // bf16 rows, 16 uint4 each
#pragma unroll
        for (int j = 0; j < 8; j++) {
            int idx = t + j * 256;             // 2048 uint4 = 128 rows
            int r = idx >> 4, seg = idx & 15;
            uint4 v = make_uint4(0, 0, 0, 0);
            if (row0 + r < n) v = Ab[(size_t)(row0 + r) * 16 + seg];
            float f[8];
            f[0] = blo2f(v.x); f[1] = bhi2f(v.x);
            f[2] = blo2f(v.y); f[3] = bhi2f(v.y);
            f[4] = blo2f(v.z); f[5] = bhi2f(v.z);
            f[6] = blo2f(v.w); f[7] = bhi2f(v.w);
            unsigned short us[8];
#pragma unroll
            for (int k = 0; k < 8; k++) {
                int c = seg * 8 + k;
                float z = fmaf(f[k], lsc[c], lsh[c]);
                z = z > 0.f ? z : __expf(z) - 1.f;
                us[k] = f2b(z);
            }
            ushort4 u0, u1;
            u0.x = us[0]; u0.y = us[1]; u0.z = us[2]; u0.w = us[3];
            u1.x = us[4]; u1.y = us[5]; u1.z = us[6]; u1.w = us[7];
            *(ushort4*)&lA[r][seg * 8] = u0;
            *(ushort4*)&lA[r][seg * 8 + 4] = u1;
        }
    } else {
        const float* Af = (const float*)Ain;
#pragma unroll
        for (int j = 0; j < 16; j++) {
            int idx = t + j * 256;             // 4096 float4 = 128 rows
            int r = idx >> 5, c4 = idx & 31;
            float4 v = make_float4(0.f, 0.f, 0.f, 0.f);
            if (row0 + r < n) v = ((const float4*)Af)[(size_t)(row0 + r) * 32 + c4];
            ushort4 u;
            u.x = f2b(v.x); u.y = f2b(v.y); u.z = f2b(v.z); u.w = f2b(v.w);
            *(ushort4*)&lA[r][c4 * 4] = u;
        }
    }
    __syncthreads();

    int w = t >> 6, lane = t & 63;
    int m = lane & 15, q = lane >> 4;
    int ar0 = w * 32 + m, ar1 = w * 32 + 16 + m;   // two 16-row tiles per wave
    floatx4 acc0[8], acc1[8];
#pragma unroll
    for (int ct = 0; ct < 8; ct++) { acc0[ct] = (floatx4)0.0f; acc1[ct] = (floatx4)0.0f; }

#pragma unroll
    for (int kt = 0; kt < 4; kt++) {
        int kb = kt * 32 + q * 8;
        short8 af0 = *(const short8*)&lA[ar0][kb];
        short8 af1 = *(const short8*)&lA[ar1][kb];
#pragma unroll
        for (int ct = 0; ct < 8; ct++) {
            short8 bf = *(const short8*)&lW[ct * 16 + m][kb];
            acc0[ct] = __builtin_amdgcn_mfma_f32_16x16x32_bf16(af0, bf, acc0[ct], 0, 0, 0);
            acc1[ct] = __builtin_amdgcn_mfma_f32_16x16x32_bf16(af1, bf, acc1[ct], 0, 0, 0);
        }
    }

    __syncthreads();   // all waves done with lA/lW as inputs
#pragma unroll
    for (int ct = 0; ct < 8; ct++)
#pragma unroll
        for (int r = 0; r < 4; r++) {
            lA[w * 32 + q * 4 + r][ct * 16 + m] = f2b(acc0[ct][r]);
            lA[w * 32 + 16 + q * 4 + r][ct * 16 + m] = f2b(acc1[ct][r]);
        }
    __syncthreads();
#pragma unroll
    for (int j = 0; j < 8; j++) {
        int idx = t + j * 256;                 // 2048 uint4 stores
        int r = idx >> 4, seg = idx & 15;
        int grow = row0 + r;
        if (grow < n) {
            uint4 v = *(const uint4*)&lA[r][seg * 8];
            ((uint4*)hB)[(size_t)grow * 16 + seg] = v;
        }
    }
    // fused attention scores: 2 threads per row, 64 chans each (dword LDS reads)
    int r = t >> 1, q2 = t & 1;
    float s1 = 0.f, s2 = 0.f;
#pragma unroll
    for (int k = 0; k < 32; k++) {
        int c = q2 * 64 + 2 * k;
        unsigned int u = *(const unsigned int*)&lA[r][c];
        float va = blo2f(u), vb = bhi2f(u);
        s1 += va * las[c] + vb * las[c + 1];
        s2 += va * lad[c] + vb * lad[c + 1];
    }
    s1 += __shfl_xor(s1, 1, 64);
    s2 += __shfl_xor(s2, 1, 64);
    if (q2 == 0 && row0 + r < n) { es[row0 + r] = s1; ed[row0 + r] = s2; }
}

// ---------------- fused softmax + weighted gather (half-wave per node) ----------
// one pass: no max subtraction (scores bounded |e| << 88, exp safe in fp32;
// alpha = p/den is shift-invariant so result identical)
__global__ __launch_bounds__(256) void k_attn(const unsigned short* __restrict__ hB,
                                              const int* __restrict__ srcs,
                                              const int* __restrict__ rowptr,
                                              const float* __restrict__ es,
                                              const float* __restrict__ ed,
                                              const float* __restrict__ bias,
                                              unsigned short* __restrict__ haggB, int n) {
    int w = (blockIdx.x * 256 + threadIdx.x) >> 5;   // node per half-wave
    if (w >= n) return;
    int lane32 = threadIdx.x & 31;
    int g = lane32 >> 4, l16 = lane32 & 15;
    int base = threadIdx.x & 32;                     // this half's lane offset in wave
    int start = rowptr[w], end = rowptr[w + 1];
    float edv = ed[w];
    const uint4* hp4 = (const uint4*)hB;
    floatx2 a0 = {0.f, 0.f}, a1 = {0.f, 0.f}, a2 = {0.f, 0.f}, a3 = {0.f, 0.f};
    float den = 0.f;

    for (int chunk = start; chunk < end; chunk += 32) {
        int i = chunk + lane32;
        int sv = 0; float pv = 0.f;
        if (i < end) {
            sv = srcs[i];
            float e = es[sv] + edv;
            e = e > 0.f ? e : NEG * e;
            pv = __expf(e);
            den += pv;
        }
        int cnt = min(32, end - chunk);
        for (int j = 0; j < cnt; j += 4) {           // 2 groups x 2 edges per iter
            int   s0 = __shfl(sv, base + j + g, 64);
            float p0 = __shfl(pv, base + j + g, 64);
            int   s1 = __shfl(sv, base + j + 2 + g, 64);
            float p1 = __shfl(pv, base + j + 2 + g, 64);
            if (p0 != 0.f) {
                uint4 h0 = hp4[(size_t)s0 * 16 + l16];
                floatx2 P = {p0, p0};
                a0 += P * u2f2(h0.x); a1 += P * u2f2(h0.y);
                a2 += P * u2f2(h0.z); a3 += P * u2f2(h0.w);
            }
            if (p1 != 0.f) {
                uint4 h1 = hp4[(size_t)s1 * 16 + l16];
                floatx2 P = {p1, p1};
                a0 += P * u2f2(h1.x); a1 += P * u2f2(h1.y);
                a2 += P * u2f2(h1.z); a3 += P * u2f2(h1.w);
            }
        }
    }
    den += __shfl_xor(den, 1, 64);  den += __shfl_xor(den, 2, 64);
    den += __shfl_xor(den, 4, 64);  den += __shfl_xor(den, 8, 64);
    den += __shfl_xor(den, 16, 64);
    a0.x += __shfl_xor(a0.x, 16, 64); a0.y += __shfl_xor(a0.y, 16, 64);
    a1.x += __shfl_xor(a1.x, 16, 64); a1.y += __shfl_xor(a1.y, 16, 64);
    a2.x += __shfl_xor(a2.x, 16, 64); a2.y += __shfl_xor(a2.y, 16, 64);
    a3.x += __shfl_xor(a3.x, 16, 64); a3.y += __shfl_xor(a3.y, 16, 64);
    if (g == 0) {
        float inv = 1.f / den;                       // den > 0: self loop guaranteed
        const float2* b2p = (const float2*)bias;
        float2 c0 = b2p[l16 * 4 + 0], c1 = b2p[l16 * 4 + 1];
        float2 c2 = b2p[l16 * 4 + 2], c3 = b2p[l16 * 4 + 3];
        uint4 o;
        o.x = (unsigned int)f2b(fmaf(a0.x, inv, c0.x)) |
              ((unsigned int)f2b(fmaf(a0.y, inv, c0.y)) << 16);
        o.y = (unsigned int)f2b(fmaf(a1.x, inv, c1.x)) |
              ((unsigned int)f2b(fmaf(a1.y, inv, c1.y)) << 16);
        o.z = (unsigned int)f2b(fmaf(a2.x, inv, c2.x)) |
              ((unsigned int)f2b(fmaf(a2.y, inv, c2.y)) << 16);
        o.w = (unsigned int)f2b(fmaf(a3.x, inv, c3.x)) |
              ((unsigned int)f2b(fmaf(a3.y, inv, c3.y)) << 16);
        ((uint4*)haggB)[(size_t)w * 16 + l16] = o;
    }
}

// ---------------- BatchNorm stats from bf16 hagg ----------------
__global__ __launch_bounds__(256) void k_bnstats(const unsigned short* __restrict__ hin,
                                                 float* sums, float* sqs, int n) {
    __shared__ float red[4][256];
    int t = threadIdx.x;
    int c2 = t & 63, quarter = t >> 6;
    int r0 = blockIdx.x * 256;
    int rend = min(r0 + 256, n);
    const unsigned int* hp = (const unsigned int*)hin;
    float s0 = 0.f, q0 = 0.f, s1 = 0.f, q1 = 0.f;
    for (int r = r0 + quarter; r < rend; r += 4) {
        unsigned int v = hp[(size_t)r * 64 + c2];
        float a = blo2f(v), b = bhi2f(v);
        s0 += a; q0 += a * a;
        s1 += b; q1 += b * b;
    }
    *(float4*)&red[quarter][c2 * 4] = make_float4(s0, q0, s1, q1);
    __syncthreads();
    float v = red[0][t] + red[1][t] + red[2][t] + red[3][t];
    int c2i = t >> 2, k = t & 3;
    int ch = c2i * 2 + (k >> 1);
    if (k & 1) atomicAdd(&sqs[ch], v);
    else       atomicAdd(&sums[ch], v);
}

// ---------------- output head: BN+ELU on bf16 in, in-block BN finalize ----------------
__global__ __launch_bounds__(256) void k_outgemm(const unsigned short* __restrict__ h,
                                                 const float* __restrict__ sums,
                                                 const float* __restrict__ sqs,
                                                 const float* __restrict__ gamma,
                                                 const float* __restrict__ beta,
                                                 const float* __restrict__ Wout,
                                                 const float* __restrict__ bout,
                                                 float* __restrict__ out, int n) {
    __shared__ float lwT[40][128];
    __shared__ float lh[64][132];
    __shared__ float lb[40];
    __shared__ float lsc[128], lsh[128];
    int t = threadIdx.x;
    if (t < 128) {
        float mu = sums[t] * (1.f / NNODES);
        float var = fmaxf(sqs[t] * (1.f / NNODES) - mu * mu, 0.f);
        float s = gamma[t] * rsqrtf(var + BNEPS);
        lsc[t] = s;
        lsh[t] = beta[t] - mu * s;
    }
    for (int idx = t; idx < 128 * 40; idx += 256) {
        int r = idx / 40, c = idx % 40;
        lwT[c][r] = Wout[idx];
    }
    if (t < 40) lb[t] = bout[t];
    __syncthreads();
    int n0 = blockIdx.x * 64;
    const uint4* hb4 = (const uint4*)h;
#pragma unroll
    for (int j = 0; j < 4; j++) {
        int idx = t + j * 256;
        int r = idx >> 4, seg = idx & 15;
        uint4 v = make_uint4(0, 0, 0, 0);
        if (n0 + r < n) v = hb4[(size_t)(n0 + r) * 16 + seg];
        float f[8];
        f[0] = blo2f(v.x); f[1] = bhi2f(v.x);
        f[2] = blo2f(v.y); f[3] = bhi2f(v.y);
        f[4] = blo2f(v.z); f[5] = bhi2f(v.z);
        f[6] = blo2f(v.w); f[7] = bhi2f(v.w);
#pragma unroll
        for (int k = 0; k < 8; k++) {
            int c = seg * 8 + k;
            float z = fmaf(f[k], lsc[c], lsh[c]);
            z = z > 0.f ? z : __expf(z) - 1.f;
            lh[r][c] = z;
        }
    }
    __syncthreads();
    int nl = t & 63, g = t >> 6;
    int row = n0 + nl;
    if (row >= n) return;
    float acc[10] = {};
    for (int k = 0; k < 128; k += 4) {
        float4 hv = *(const float4*)&lh[nl][k];
#pragma unroll
        for (int j = 0; j < 10; j++) {
            float4 wv = *(const float4*)&lwT[g * 10 + j][k];
            acc[j] += hv.x * wv.x + hv.y * wv.y + hv.z * wv.z + hv.w * wv.w;
        }
    }
#pragma unroll
    for (int j = 0; j < 10; j++)
        out[(size_t)row * 40 + g * 10 + j] = acc[j] + lb[g * 10 + j];
}

// ---------------- launch ----------------
extern "C" void kernel_launch(void* const* d_in, const int* in_sizes, int n_in,
                              void* d_out, int out_size, void* d_ws, size_t ws_size,
                              hipStream_t stream) {
    const float* x      = (const float*)d_in[0];
    const int*   ei     = (const int*)d_in[1];
    const float* W1     = (const float*)d_in[2];
    const float* a_src1 = (const float*)d_in[3];
    const float* a_dst1 = (const float*)d_in[4];
    const float* b1     = (const float*)d_in[5];
    const float* W2     = (const float*)d_in[6];
    const float* a_src2 = (const float*)d_in[7];
    const float* a_dst2 = (const float*)d_in[8];
    const float* b2     = (const float*)d_in[9];
    const float* gamma  = (const float*)d_in[10];
    const float* beta   = (const float*)d_in[11];
    const float* Wout   = (const float*)d_in[12];
    const float* bout   = (const float*)d_in[13];
    float* out = (float*)d_out;

    char* p = (char*)d_ws;
    auto alloc = [&](size_t bytes) -> void* {
        void* r = (void*)p;
        p += (bytes + 255) & ~(size_t)255;
        return r;
    };
    unsigned short* hB    = (unsigned short*)alloc((size_t)NNODES * 128 * 2);
    unsigned short* haggB = (unsigned short*)alloc((size_t)NNODES * 128 * 2);
    float* es     = (float*)alloc((size_t)NNODES * 4);
    float* ed     = (float*)alloc((size_t)NNODES * 4);
    int*   pairs  = (int*)alloc((size_t)ET * 4);
    int*   srcs   = (int*)alloc((size_t)ET * 4);
    int*   rowptr = (int*)alloc((size_t)(NNODES + 1) * 4);
    int*   bcnt   = (int*)alloc(800 * 4);
    int*   bbase  = (int*)alloc(800 * 4);
    int*   bcur   = (int*)alloc(800 * 4);
    float* bnstat = (float*)alloc(4 * 128 * 4);
    unsigned short* WT1 = (unsigned short*)alloc(128 * 128 * 2);
    unsigned short* WT2 = (unsigned short*)alloc(128 * 128 * 2);
    int*   flag   = (int*)alloc(4);
    int*   done   = (int*)alloc(4);

    float* sum1 = bnstat, *sq1 = bnstat + 128, *sum2 = bnstat + 256, *sq2 = bnstat + 384;

    k_prep<<<64, 256, 0, stream>>>(W1, W2, WT1, WT2, ei, flag, bcnt, done, bnstat);
    k_bhist<<<NBLK_E, 256, 0, stream>>>(ei, flag, bcnt, done, bbase, bcur);
    k_bscatter<<<NBLK_E, 256, 0, stream>>>(ei, flag, bcur, pairs);
    k_bsort<<<NBUCK, 256, 0, stream>>>(pairs, bbase, rowptr, srcs);

    const int GB = (NNODES + 127) / 128;          // 782 (gemm tiles)
    const int AB = NNODES / 8;                    // 12500 (8 nodes/block, exact)
    const int SB = (NNODES + 255) / 256;          // 391
    const int OB = (NNODES + 63) / 64;            // 1563

    // ---- layer 1 ----
    k_gemm<false><<<GB, 256, 0, stream>>>(x, WT1, nullptr, nullptr, nullptr, nullptr,
                                          a_src1, a_dst1, es, ed, hB, NNODES);
    k_attn<<<AB, 256, 0, stream>>>(hB, srcs, rowptr, es, ed, b1, haggB, NNODES);
    k_bnstats<<<SB, 256, 0, stream>>>(haggB, sum1, sq1, NNODES);

    // ---- layer 2 (BN+ELU finalized+fused in A-staging) ----
    k_gemm<true><<<GB, 256, 0, stream>>>(haggB, WT2, sum1, sq1, gamma, beta,
                                         a_src2, a_dst2, es, ed, hB, NNODES);
    k_attn<<<AB, 256, 0, stream>>>(hB, srcs, rowptr, es, ed, b2, haggB, NNODES);
    k_bnstats<<<SB, 256, 0, stream>>>(haggB, sum2, sq2, NNODES);

    // ---- head (BN finalize + ELU fused into staging) ----
    k_outgemm<<<OB, 256, 0, stream>>>(haggB, sum2, sq2, gamma, beta, Wout, bout, out, NNODES);

    (void)in_sizes; (void)n_in; (void)out_size; (void)ws_size;
}